// Round 2
// baseline (84.060 us; speedup 1.0000x reference)
//
#include <hip/hip_runtime.h>

// CenterLoss: scalar = 0.003 * ( sum_b clamp(||e_b - c_{l_b}||^2, 1e-12, 1e12)
//                                + B*(C-1)*1e-12 ) / B
// B=4096, D=512, C=10000, all fp32; labels int.
//
// Single fused kernel: one 64-lane wave per row, block-reduce 4 rows,
// one fp32 atomicAdd per block into d_out (zero-initialized via
// hipMemsetAsync, which is graph-capture legal). Saves the second
// dispatch's launch latency and avoids d_ws entirely.

#define LAMBDA_C  0.003f
#define CLAMP_MIN 1e-12f
#define CLAMP_MAX 1e12f

static constexpr int B = 4096;
static constexpr int D = 512;
static constexpr int C = 10000;

__global__ __launch_bounds__(256) void center_loss_kernel(
    const float* __restrict__ emb,
    const int*   __restrict__ labels,
    const float* __restrict__ centers,
    float*       __restrict__ out)
{
    const int wave = threadIdx.x >> 6;          // 0..3
    const int lane = threadIdx.x & 63;
    const int row  = (blockIdx.x << 2) + wave;  // 0..4095

    const int label = labels[row];
    const float4* e4 = (const float4*)(emb     + (size_t)row   * D);
    const float4* c4 = (const float4*)(centers + (size_t)label * D);

    // D=512 -> 128 float4 per row; 64 lanes x 2 float4 each, coalesced.
    float s = 0.0f;
#pragma unroll
    for (int k = 0; k < 2; ++k) {
        const float4 e = e4[lane + (k << 6)];
        const float4 c = c4[lane + (k << 6)];
        const float dx = e.x - c.x;
        const float dy = e.y - c.y;
        const float dz = e.z - c.z;
        const float dw = e.w - c.w;
        s += dx * dx + dy * dy + dz * dz + dw * dw;
    }

    // 64-lane wave reduction
#pragma unroll
    for (int off = 32; off > 0; off >>= 1)
        s += __shfl_down(s, off, 64);

    // Per-row clamp happens BEFORE the sum over rows.
    __shared__ float rowsum[4];
    if (lane == 0)
        rowsum[wave] = fminf(fmaxf(s, CLAMP_MIN), CLAMP_MAX);
    __syncthreads();

    if (threadIdx.x == 0) {
        float t = rowsum[0] + rowsum[1] + rowsum[2] + rowsum[3];
        float v = LAMBDA_C * (t / (float)B);
        if (blockIdx.x == 0) {
            // constant floor from the C-1 masked-out entries per row
            v += LAMBDA_C * (((float)B * (float)(C - 1) * CLAMP_MIN) / (float)B);
        }
        atomicAdd(out, v);   // device-scope by default on CDNA
    }
}

extern "C" void kernel_launch(void* const* d_in, const int* in_sizes, int n_in,
                              void* d_out, int out_size, void* d_ws, size_t ws_size,
                              hipStream_t stream)
{
    const float* emb     = (const float*)d_in[0];   // [B, D] fp32
    const int*   labels  = (const int*)  d_in[1];   // [B] int
    const float* centers = (const float*)d_in[2];   // [C, D] fp32
    float*       out     = (float*)d_out;           // [1] fp32

    hipMemsetAsync(out, 0, sizeof(float), stream);  // graph-capture legal
    center_loss_kernel<<<B / 4, 256, 0, stream>>>(emb, labels, centers, out);
}